// Round 4
// baseline (883.379 us; speedup 1.0000x reference)
//
#include <hip/hip_runtime.h>

#define B_ 4
#define V_ 256
#define H_ 128
#define H2_ 64
#define NL_ 3
#define BV_ 1024  // B*V

typedef unsigned short bhalf;  // bf16 bits (internal storage; all I/O fp32)
using bf16x8 = __attribute__((ext_vector_type(8))) short;
using f32x4  = __attribute__((ext_vector_type(4))) float;

__device__ __forceinline__ float bf2f(bhalf u) {
  return __uint_as_float(((unsigned)u) << 16);
}
__device__ __forceinline__ bhalf f2bf(float f) {
  unsigned u = __float_as_uint(f);
  return (bhalf)((u + 0x7FFFu + ((u >> 16) & 1u)) >> 16);
}
__device__ __forceinline__ unsigned pack2(float a, float b) {
  return (unsigned)f2bf(a) | ((unsigned)f2bf(b) << 16);
}
__device__ __forceinline__ void unpack8(uint4 p, float* d) {
  d[0] = bf2f((bhalf)(p.x & 0xffff)); d[1] = bf2f((bhalf)(p.x >> 16));
  d[2] = bf2f((bhalf)(p.y & 0xffff)); d[3] = bf2f((bhalf)(p.y >> 16));
  d[4] = bf2f((bhalf)(p.z & 0xffff)); d[5] = bf2f((bhalf)(p.z >> 16));
  d[6] = bf2f((bhalf)(p.w & 0xffff)); d[7] = bf2f((bhalf)(p.w >> 16));
}

// Keep the harness-named kernel symbol.
__global__ void VRPValueNet_66924180407123_kernel() {}

__global__ void k_init(float* out_acc) {
  if (threadIdx.x < 4) out_acc[threadIdx.x] = 0.f;
}

// ---------------- prep: UeT[l][h][k] = bf16(Ue[l][k][h]) ----------------
__global__ void __launch_bounds__(256) k_prep(const float* __restrict__ Ue,
                                              bhalf* __restrict__ UeT) {
  int l = blockIdx.x, t = threadIdx.x;
  const float* src = Ue + l * H_ * H_;
  bhalf* dst = UeT + l * H_ * H_;
#pragma unroll
  for (int it = 0; it < 64; ++it) {
    int idx = it * 256 + t;          // idx = h*128 + k
    int h = idx >> 7, k = idx & 127;
    dst[idx] = f2bf(src[k * H_ + h]);  // write coalesced, read strided (L2)
  }
}

// ---------------- node embedding ----------------
__global__ void k0_x(const float* __restrict__ coord, const float* __restrict__ W_node,
                     const float* __restrict__ b_node, float* __restrict__ x) {
  int bi = blockIdx.x, h = threadIdx.x;
  float c0 = coord[bi * 3 + 0];
  float c1 = coord[bi * 3 + 1];
  float c2 = coord[bi * 3 + 2];
  float a = b_node[h] + c0 * W_node[h] + c1 * W_node[H_ + h] + c2 * W_node[2 * H_ + h];
  x[(size_t)bi * H_ + h] = a;
}

// ---------------- edge embedding (e stored bf16 row-major) ----------------
__global__ void __launch_bounds__(256) k0_e(
    const float* __restrict__ xev, const float* __restrict__ xt,
    const float* __restrict__ xbt,
    const float* __restrict__ W_eval, const float* __restrict__ b_eval,
    const float* __restrict__ W_ecat, const float* __restrict__ b_ecat,
    bhalf* __restrict__ e) {
  int bi = blockIdx.x;
  int t = threadIdx.x;
  int jj = t >> 7, h = t & 127;
  float w0, w1 = 0.f, b0;
  if (h < H2_) { w0 = W_eval[h]; b0 = b_eval[h]; }
  else { int h2 = h - H2_; w0 = W_ecat[h2]; w1 = W_ecat[H2_ + h2]; b0 = b_ecat[h2]; }
  for (int jt = 0; jt < 128; ++jt) {
    int j = jt * 2 + jj;
    size_t ei = (size_t)bi * V_ + j;
    float val;
    if (h < H2_) val = xev[ei] * w0 + b0;
    else         val = xt[ei] * w0 + xbt[ei] * w1 + b0;
    e[ei * H_ + h] = f2bf(val);
  }
}

// ---------------- per-layer x projections: VV=(Vex,Vnx), Unx ----------------
__global__ void k1_xproj(const float* __restrict__ x,
                         const float* __restrict__ Ve, const float* __restrict__ bVe,
                         const float* __restrict__ Vn, const float* __restrict__ bVn,
                         const float* __restrict__ Un, const float* __restrict__ bUn,
                         float2* __restrict__ VV, float* __restrict__ Unx) {
  __shared__ float xs[H_];
  int bi = blockIdx.x, h = threadIdx.x;
  xs[h] = x[(size_t)bi * H_ + h];
  __syncthreads();
  float av = bVe[h], an = bVn[h], au = bUn[h];
#pragma unroll 8
  for (int k = 0; k < H_; ++k) {
    float xv = xs[k];
    av += xv * Ve[k * H_ + h];
    an += xv * Vn[k * H_ + h];
    au += xv * Un[k * H_ + h];
  }
  size_t o = (size_t)bi * H_ + h;
  VV[o] = make_float2(av, an);
  Unx[o] = au;
}

// ---------------- MFMA fused edge pass ----------------
// block = (b,i). 2 passes of 128 j. wave tile 64j x 64h (4x4 frags of 16x16x32).
// e_tmp = e@Ue + bUe + Vex_i + Vex_j; sigma-gated agg + BN partial stats;
// e_tmp stored (bf16 row-major) via XOR-swizzled LDS bounce iff et != null.
__global__ void __launch_bounds__(256) k2_edge(
    const bhalf* __restrict__ e, bhalf* __restrict__ et,
    const bhalf* __restrict__ UeT_g, const float* __restrict__ bUe,
    const float2* __restrict__ VV,
    float* __restrict__ aggN, float* __restrict__ aggD,
    float* __restrict__ bn_ps, float* __restrict__ bn_ps2) {
  __shared__ __align__(16) bhalf UeT_s[H_ * H_];  // 32 KB, rows = h, XOR-swizzled chunks
  __shared__ __align__(16) bhalf es[128 * H_];    // 32 KB, rows = j (tile), swizzled; reused as bounce + red
  __shared__ float cvi_s[H_];

  const int t = threadIdx.x;
  const int bi = blockIdx.x;
  const int b = bi >> 8;
  const int lane = t & 63, w = t >> 6;
  const int c = lane & 15, q = lane >> 4;
  const int jw = w & 1, hw = w >> 1;

  // ---- stage UeT (global pre-transposed bf16 -> swizzled LDS) ----
  {
    const uint4* src = (const uint4*)(UeT_g);
#pragma unroll
    for (int r = 0; r < 8; ++r) {
      int slot = r * 256 + t;            // 16B chunk id: row*16 + ck
      int row = slot >> 4, ck = slot & 15;
      uint4 v = src[slot];
      *(uint4*)&UeT_s[row * H_ + ((ck ^ (row & 15)) * 8)] = v;
    }
  }
  if (t < H_) cvi_s[t] = bUe[t] + VV[(size_t)bi * H_ + t].x;

  float aN[4] = {0, 0, 0, 0}, aD[4] = {0, 0, 0, 0};
  float bS[4] = {0, 0, 0, 0}, bS2[4] = {0, 0, 0, 0};

  for (int p = 0; p < 2; ++p) {
    // ---- stage e tile (128 j x 128 k bf16), swizzled ----
    {
      const uint4* src = (const uint4*)(e + ((size_t)bi * V_ + p * 128) * H_);
#pragma unroll
      for (int r = 0; r < 8; ++r) {
        int slot = r * 256 + t;
        int row = slot >> 4, ck = slot & 15;
        uint4 v = src[slot];
        *(uint4*)&es[row * H_ + ((ck ^ (row & 15)) * 8)] = v;
      }
    }
    __syncthreads();

    // ---- K loop ----
    f32x4 acc[4][4];
#pragma unroll
    for (int m = 0; m < 4; ++m)
#pragma unroll
      for (int n = 0; n < 4; ++n) acc[m][n] = {0.f, 0.f, 0.f, 0.f};
#pragma unroll
    for (int k0 = 0; k0 < 4; ++k0) {
      bf16x8 af[4], bf[4];
#pragma unroll
      for (int m = 0; m < 4; ++m) {
        int row = jw * 64 + m * 16 + c;
        af[m] = *(const bf16x8*)&es[row * H_ + (((k0 * 4 + q) ^ c) * 8)];
      }
#pragma unroll
      for (int n = 0; n < 4; ++n) {
        int row = hw * 64 + n * 16 + c;
        bf[n] = *(const bf16x8*)&UeT_s[row * H_ + (((k0 * 4 + q) ^ c) * 8)];
      }
#pragma unroll
      for (int m = 0; m < 4; ++m)
#pragma unroll
        for (int n = 0; n < 4; ++n)
          acc[m][n] = __builtin_amdgcn_mfma_f32_16x16x32_bf16(af[m], bf[n], acc[m][n], 0, 0, 0);
    }
    __syncthreads();  // all waves done reading es; es becomes bounce buffer

    // ---- epilogue: et, sigmoid, agg/BN partials, bounce write ----
#pragma unroll
    for (int m = 0; m < 4; ++m) {
#pragma unroll
      for (int n = 0; n < 4; ++n) {
#pragma unroll
        for (int r = 0; r < 4; ++r) {
          int j_ip = jw * 64 + m * 16 + q * 4 + r;   // j within pass tile
          int j = p * 128 + j_ip;
          int h = hw * 64 + n * 16 + c;
          float2 vv = VV[((size_t)b * V_ + j) * H_ + h];
          float etv = acc[m][n][r] + cvi_s[h] + vv.x;
          float g = 1.f / (1.f + __expf(-etv));
          aN[n] += g * vv.y; aD[n] += g; bS[n] += etv; bS2[n] += etv * etv;
          if (et != 0) {
            int hc = h >> 3;
            es[j_ip * H_ + ((hc ^ (q * 4 + r)) * 8) + (h & 7)] = f2bf(etv);
          }
        }
      }
    }
    __syncthreads();

    // ---- coalesced readout of bounce -> e_tmp (row-major) ----
    if (et != 0) {
#pragma unroll
      for (int it = 0; it < 4; ++it) {
        int slot = it * 256 + t;
        int jj = slot >> 4, ck = slot & 15;
        uint4 v = *(const uint4*)&es[jj * H_ + ((ck ^ (jj & 15)) * 8)];
        *(uint4*)&et[(((size_t)bi * V_) + p * 128 + jj) * H_ + ck * 8] = v;
      }
    }
    __syncthreads();
  }

  // ---- reductions: over q via shfl, over waves via LDS ----
#pragma unroll
  for (int n = 0; n < 4; ++n) {
    aN[n] += __shfl_xor(aN[n], 16);  aN[n] += __shfl_xor(aN[n], 32);
    aD[n] += __shfl_xor(aD[n], 16);  aD[n] += __shfl_xor(aD[n], 32);
    bS[n] += __shfl_xor(bS[n], 16);  bS[n] += __shfl_xor(bS[n], 32);
    bS2[n] += __shfl_xor(bS2[n], 16); bS2[n] += __shfl_xor(bS2[n], 32);
  }
  float* red = (float*)es;  // 4 arrays x 4 waves x 64 = 4096 floats = 16 KB
  if (lane < 16) {
#pragma unroll
    for (int n = 0; n < 4; ++n) {
      int hl = n * 16 + c;
      red[(0 * 4 + w) * 64 + hl] = aN[n];
      red[(1 * 4 + w) * 64 + hl] = aD[n];
      red[(2 * 4 + w) * 64 + hl] = bS[n];
      red[(3 * 4 + w) * 64 + hl] = bS2[n];
    }
  }
  __syncthreads();
  if (t < H_) {
    int hw2 = t >> 6, hl = t & 63;
    int w0 = hw2 * 2, w1 = w0 + 1;
    size_t o = (size_t)bi * H_ + t;
    aggN[o]   = red[(0 * 4 + w0) * 64 + hl] + red[(0 * 4 + w1) * 64 + hl];
    aggD[o]   = red[(1 * 4 + w0) * 64 + hl] + red[(1 * 4 + w1) * 64 + hl];
    bn_ps[o]  = red[(2 * 4 + w0) * 64 + hl] + red[(2 * 4 + w1) * 64 + hl];
    bn_ps2[o] = red[(3 * 4 + w0) * 64 + hl] + red[(3 * 4 + w1) * 64 + hl];
  }
}

// ---------------- finalize e BN stats ----------------
__global__ void __launch_bounds__(256) k3_estats(const float* __restrict__ bn_ps,
                                                 const float* __restrict__ bn_ps2,
                                                 float* __restrict__ mu_rs) {
  __shared__ float r1[256], r2[256];
  int h = blockIdx.x, t = threadIdx.x;
  float s = 0, s2 = 0;
#pragma unroll
  for (int r = 0; r < 4; ++r) {
    int blk = r * 256 + t;
    s += bn_ps[(size_t)blk * H_ + h];
    s2 += bn_ps2[(size_t)blk * H_ + h];
  }
  r1[t] = s; r2[t] = s2; __syncthreads();
  for (int st = 128; st > 0; st >>= 1) {
    if (t < st) { r1[t] += r1[t + st]; r2[t] += r2[t + st]; }
    __syncthreads();
  }
  if (t == 0) {
    const float inv = 1.f / 262144.f;
    float mu = r1[0] * inv;
    float var = r2[0] * inv - mu * mu;
    mu_rs[h] = mu;
    mu_rs[H_ + h] = rsqrtf(var + 1e-5f);
  }
}

// ---------------- x update ----------------
__global__ void __launch_bounds__(256) k4_xupd(float* __restrict__ x,
                                               const float* __restrict__ Unx,
                                               const float* __restrict__ aggN,
                                               const float* __restrict__ aggD,
                                               const float* __restrict__ g_x,
                                               const float* __restrict__ bx_bn) {
  __shared__ float red[256], red2[256];
  int h = blockIdx.x, t = threadIdx.x;
  float xt[4];
  float s = 0, s2 = 0;
#pragma unroll
  for (int r = 0; r < 4; ++r) {
    int idx = r * 256 + t;
    size_t o = (size_t)idx * H_ + h;
    float v = Unx[o] + aggN[o] / (aggD[o] + 1e-20f);
    xt[r] = v; s += v; s2 += v * v;
  }
  red[t] = s; red2[t] = s2; __syncthreads();
  for (int st = 128; st > 0; st >>= 1) {
    if (t < st) { red[t] += red[t + st]; red2[t] += red2[t + st]; }
    __syncthreads();
  }
  float mu = red[0] * (1.f / 1024.f);
  float var = red2[0] * (1.f / 1024.f) - mu * mu;
  float rs = rsqrtf(var + 1e-5f);
  float g = g_x[h], bb = bx_bn[h];
#pragma unroll
  for (int r = 0; r < 4; ++r) {
    int idx = r * 256 + t;
    size_t o = (size_t)idx * H_ + h;
    float v = g * (xt[r] - mu) * rs + bb;
    if (v > 0.f) x[o] += v;
  }
}

// ---------------- e update from stored e_tmp ----------------
__global__ void __launch_bounds__(256) k5_eupd(bhalf* __restrict__ e,
                                               const bhalf* __restrict__ e_tmp,
                                               const float* __restrict__ g_e,
                                               const float* __restrict__ be_bn,
                                               const float* __restrict__ mu_rs) {
  __shared__ float sc[H_], sh[H_];
  int t = threadIdx.x;
  if (t < H_) {
    float mu = mu_rs[t], rs = mu_rs[H_ + t];
    float g = g_e[t], bb = be_bn[t];
    sc[t] = g * rs;
    sh[t] = bb - g * rs * mu;
  }
  __syncthreads();
  size_t base = ((size_t)blockIdx.x * 256 + t) * 8;
  int h0 = (int)(base & 127);
  uint4 pe = *(const uint4*)(e + base);
  uint4 pt = *(const uint4*)(e_tmp + base);
  float ev[8], tv[8];
  unpack8(pe, ev); unpack8(pt, tv);
#pragma unroll
  for (int m = 0; m < 8; ++m) {
    int h = h0 + m;
    float v = sc[h] * tv[m] + sh[h];
    if (v > 0.f) ev[m] += v;
  }
  uint4 st;
  st.x = pack2(ev[0], ev[1]); st.y = pack2(ev[2], ev[3]);
  st.z = pack2(ev[4], ev[5]); st.w = pack2(ev[6], ev[7]);
  *(uint4*)(e + base) = st;
}

// ---------------- readout ----------------
__global__ void k6_readout(const float* __restrict__ x, const float* __restrict__ W1,
                           const float* __restrict__ b1, const float* __restrict__ W2,
                           float* __restrict__ out_acc) {
  __shared__ float xs[H_];
  __shared__ float red[H_];
  int bi = blockIdx.x, h = threadIdx.x;
  int b = bi >> 8;
  xs[h] = x[(size_t)bi * H_ + h];
  __syncthreads();
  float a = b1[h];
#pragma unroll 8
  for (int k = 0; k < H_; ++k) a += xs[k] * W1[k * H_ + h];
  a = fmaxf(a, 0.f) * W2[h];
  red[h] = a; __syncthreads();
  for (int s = 64; s > 0; s >>= 1) {
    if (h < s) red[h] += red[h + s];
    __syncthreads();
  }
  if (h == 0) atomicAdd(&out_acc[b], red[0]);
}

__global__ void k7_final(const float* __restrict__ out_acc,
                         const float* __restrict__ b_mlp2, float* __restrict__ out) {
  int t = threadIdx.x;
  if (t < 4) out[t] = out_acc[t] * (1.f / 256.f) + b_mlp2[0];
}

extern "C" void kernel_launch(void* const* d_in, const int* in_sizes, int n_in,
                              void* d_out, int out_size, void* d_ws, size_t ws_size,
                              hipStream_t stream) {
  (void)in_sizes; (void)out_size; (void)ws_size;
  const int off = n_in - 26;  // tolerate pruned x_edges
  const float* x_ev    = (const float*)d_in[off + 0];
  const float* x_coord = (const float*)d_in[off + 1];
  const float* x_tour  = (const float*)d_in[off + 2];
  const float* x_btour = (const float*)d_in[off + 3];
  const float* W_node  = (const float*)d_in[off + 4];
  const float* b_node  = (const float*)d_in[off + 5];
  const float* W_eval  = (const float*)d_in[off + 6];
  const float* b_eval  = (const float*)d_in[off + 7];
  const float* W_ecat  = (const float*)d_in[off + 8];
  const float* b_ecat  = (const float*)d_in[off + 9];
  const float* Ue      = (const float*)d_in[off + 10];
  const float* bUe     = (const float*)d_in[off + 11];
  const float* Ve      = (const float*)d_in[off + 12];
  const float* bVe     = (const float*)d_in[off + 13];
  const float* Un      = (const float*)d_in[off + 14];
  const float* bUn     = (const float*)d_in[off + 15];
  const float* Vn      = (const float*)d_in[off + 16];
  const float* bVn     = (const float*)d_in[off + 17];
  const float* g_e     = (const float*)d_in[off + 18];
  const float* be_bn   = (const float*)d_in[off + 19];
  const float* g_x     = (const float*)d_in[off + 20];
  const float* bx_bn   = (const float*)d_in[off + 21];
  const float* W_mlp1  = (const float*)d_in[off + 22];
  const float* b_mlp1  = (const float*)d_in[off + 23];
  const float* W_mlp2  = (const float*)d_in[off + 24];
  const float* b_mlp2  = (const float*)d_in[off + 25];

  char* ws = (char*)d_ws;
  float*  x      = (float*)(ws + 0x000000);
  float2* VV     = (float2*)(ws + 0x080000);   // 1 MB: (Vex,Vnx) pairs
  float*  Unx    = (float*)(ws + 0x180000);
  float*  aggN   = (float*)(ws + 0x200000);
  float*  aggD   = (float*)(ws + 0x280000);
  float*  bn_ps  = (float*)(ws + 0x300000);
  float*  bn_ps2 = (float*)(ws + 0x380000);
  float*  mu_rs  = (float*)(ws + 0x400000);
  float*  out_acc= (float*)(ws + 0x400400);
  bhalf*  UeT_g  = (bhalf*)(ws + 0x401000);    // 3 x 32 KB pre-transposed bf16
  bhalf*  e      = (bhalf*)(ws + 0x420000);                // 64 MiB
  bhalf*  e_tmp  = (bhalf*)(ws + 0x420000 + 0x4000000);    // 64 MiB

  k_init<<<1, 64, 0, stream>>>(out_acc);
  VRPValueNet_66924180407123_kernel<<<1, 64, 0, stream>>>();
  k_prep<<<NL_, 256, 0, stream>>>(Ue, UeT_g);
  k0_x<<<BV_, H_, 0, stream>>>(x_coord, W_node, b_node, x);
  k0_e<<<BV_, 256, 0, stream>>>(x_ev, x_tour, x_btour, W_eval, b_eval, W_ecat, b_ecat, e);

  for (int l = 0; l < NL_; ++l) {
    const float* Ve_l = Ve + l * H_ * H_;
    const float* Un_l = Un + l * H_ * H_;
    const float* Vn_l = Vn + l * H_ * H_;
    const float* bUe_l = bUe + l * H_;
    const float* bVe_l = bVe + l * H_;
    const float* bUn_l = bUn + l * H_;
    const float* bVn_l = bVn + l * H_;
    const float* g_e_l = g_e + l * H_;
    const float* be_l  = be_bn + l * H_;
    const float* g_x_l = g_x + l * H_;
    const float* bx_l  = bx_bn + l * H_;
    const bhalf* UeT_l = UeT_g + l * H_ * H_;
    const bool need_e_next = (l < NL_ - 1);

    k1_xproj<<<BV_, H_, 0, stream>>>(x, Ve_l, bVe_l, Vn_l, bVn_l, Un_l, bUn_l, VV, Unx);
    k2_edge<<<BV_, 256, 0, stream>>>(e, need_e_next ? e_tmp : (bhalf*)0,
                                     UeT_l, bUe_l, VV, aggN, aggD, bn_ps, bn_ps2);
    if (need_e_next) {
      k3_estats<<<H_, 256, 0, stream>>>(bn_ps, bn_ps2, mu_rs);
      k5_eupd<<<16384, 256, 0, stream>>>(e, e_tmp, g_e_l, be_l, mu_rs);
    }
    k4_xupd<<<H_, 256, 0, stream>>>(x, Unx, aggN, aggD, g_x_l, bx_l);
  }

  k6_readout<<<BV_, H_, 0, stream>>>(x, W_mlp1, b_mlp1, W_mlp2, out_acc);
  k7_final<<<1, 64, 0, stream>>>(out_acc, b_mlp2, (float*)d_out);
}

// Round 5
// 465.835 us; speedup vs baseline: 1.8963x; 1.8963x over previous
//
#include <hip/hip_runtime.h>

#define B_ 4
#define V_ 256
#define H_ 128
#define H2_ 64
#define NL_ 3
#define BV_ 1024  // B*V

typedef unsigned short bhalf;  // bf16 bits (internal storage; all I/O fp32)
using bf16x8 = __attribute__((ext_vector_type(8))) short;
using f32x4  = __attribute__((ext_vector_type(4))) float;

__device__ __forceinline__ float bf2f(bhalf u) {
  return __uint_as_float(((unsigned)u) << 16);
}
__device__ __forceinline__ bhalf f2bf(float f) {
  unsigned u = __float_as_uint(f);
  return (bhalf)((u + 0x7FFFu + ((u >> 16) & 1u)) >> 16);
}
__device__ __forceinline__ unsigned pack2(float a, float b) {
  return (unsigned)f2bf(a) | ((unsigned)f2bf(b) << 16);
}
__device__ __forceinline__ void unpack8(uint4 p, float* d) {
  d[0] = bf2f((bhalf)(p.x & 0xffff)); d[1] = bf2f((bhalf)(p.x >> 16));
  d[2] = bf2f((bhalf)(p.y & 0xffff)); d[3] = bf2f((bhalf)(p.y >> 16));
  d[4] = bf2f((bhalf)(p.z & 0xffff)); d[5] = bf2f((bhalf)(p.z >> 16));
  d[6] = bf2f((bhalf)(p.w & 0xffff)); d[7] = bf2f((bhalf)(p.w >> 16));
}

// async 16B global->LDS. lds ptr must be wave-uniform; dest = base + lane*16.
__device__ __forceinline__ void gl2lds16(const bhalf* g, bhalf* l) {
  __builtin_amdgcn_global_load_lds(
      (const __attribute__((address_space(1))) unsigned*)g,
      (__attribute__((address_space(3))) unsigned*)l, 16, 0, 0);
}

// Keep the harness-named kernel symbol.
__global__ void VRPValueNet_66924180407123_kernel() {}

__global__ void k_init(float* out_acc) {
  if (threadIdx.x < 4) out_acc[threadIdx.x] = 0.f;
}

// ---------------- prep: UeT[l][h][k] = bf16(Ue[l][k][h]) ----------------
__global__ void __launch_bounds__(256) k_prep(const float* __restrict__ Ue,
                                              bhalf* __restrict__ UeT) {
  int l = blockIdx.x, t = threadIdx.x;
  const float* src = Ue + l * H_ * H_;
  bhalf* dst = UeT + l * H_ * H_;
#pragma unroll
  for (int it = 0; it < 64; ++it) {
    int idx = it * 256 + t;          // idx = h*128 + k
    int h = idx >> 7, k = idx & 127;
    dst[idx] = f2bf(src[k * H_ + h]);
  }
}

// ---------------- node embedding ----------------
__global__ void k0_x(const float* __restrict__ coord, const float* __restrict__ W_node,
                     const float* __restrict__ b_node, float* __restrict__ x) {
  int bi = blockIdx.x, h = threadIdx.x;
  float c0 = coord[bi * 3 + 0];
  float c1 = coord[bi * 3 + 1];
  float c2 = coord[bi * 3 + 2];
  float a = b_node[h] + c0 * W_node[h] + c1 * W_node[H_ + h] + c2 * W_node[2 * H_ + h];
  x[(size_t)bi * H_ + h] = a;
}

// ---------------- edge embedding (e bf16 row-major, uint4 stores) ----------------
__global__ void __launch_bounds__(256) k0_e(
    const float* __restrict__ xev, const float* __restrict__ xt,
    const float* __restrict__ xbt,
    const float* __restrict__ W_eval, const float* __restrict__ b_eval,
    const float* __restrict__ W_ecat, const float* __restrict__ b_ecat,
    bhalf* __restrict__ e) {
  __shared__ float w0s[H_], w1s[H_], b0s[H_];
  int bi = blockIdx.x, t = threadIdx.x;
  if (t < H_) {
    int h = t;
    if (h < H2_) { w0s[h] = W_eval[h]; w1s[h] = 0.f; b0s[h] = b_eval[h]; }
    else { int h2 = h - H2_; w0s[h] = W_ecat[h2]; w1s[h] = W_ecat[H2_ + h2]; b0s[h] = b_ecat[h2]; }
  }
  __syncthreads();
  int oct = t & 15, jt0 = t >> 4;
#pragma unroll 4
  for (int it = 0; it < 16; ++it) {
    int j = it * 16 + jt0;
    size_t ei = (size_t)bi * V_ + j;
    float v_ev = xev[ei], v_t = xt[ei], v_bt = xbt[ei];
    float vals[8];
#pragma unroll
    for (int m = 0; m < 8; ++m) {
      int h = oct * 8 + m;
      vals[m] = (h < H2_) ? (v_ev * w0s[h] + b0s[h])
                          : (v_t * w0s[h] + v_bt * w1s[h] + b0s[h]);
    }
    uint4 st;
    st.x = pack2(vals[0], vals[1]); st.y = pack2(vals[2], vals[3]);
    st.z = pack2(vals[4], vals[5]); st.w = pack2(vals[6], vals[7]);
    *(uint4*)&e[ei * H_ + oct * 8] = st;
  }
}

// ---------------- per-layer x projections: VV=(Vex,Vnx), Unx ----------------
__global__ void k1_xproj(const float* __restrict__ x,
                         const float* __restrict__ Ve, const float* __restrict__ bVe,
                         const float* __restrict__ Vn, const float* __restrict__ bVn,
                         const float* __restrict__ Un, const float* __restrict__ bUn,
                         float2* __restrict__ VV, float* __restrict__ Unx) {
  __shared__ float xs[H_];
  int bi = blockIdx.x, h = threadIdx.x;
  xs[h] = x[(size_t)bi * H_ + h];
  __syncthreads();
  float av = bVe[h], an = bVn[h], au = bUn[h];
#pragma unroll 8
  for (int k = 0; k < H_; ++k) {
    float xv = xs[k];
    av += xv * Ve[k * H_ + h];
    an += xv * Vn[k * H_ + h];
    au += xv * Un[k * H_ + h];
  }
  size_t o = (size_t)bi * H_ + h;
  VV[o] = make_float2(av, an);
  Unx[o] = au;
}

// ---------------- MFMA fused edge pass ----------------
// block = (bi, jq): 64 j-rows x 128 h. Wave tile 32j x 64h (2x4 frags 16x16x32).
// e_tmp = e@Ue + bUe + Vex_i + Vex_j; sigmoid-gated agg + BN partial stats
// (per-jq partials); e_tmp stored bf16 via swizzled LDS bounce iff et != null.
__global__ void __launch_bounds__(256, 3) k2_edge(
    const bhalf* __restrict__ e, bhalf* __restrict__ et,
    const bhalf* __restrict__ UeT_g, const float* __restrict__ bUe,
    const float2* __restrict__ VV,
    float* __restrict__ aggN, float* __restrict__ aggD,
    float* __restrict__ bn_ps, float* __restrict__ bn_ps2) {
  __shared__ __align__(16) bhalf UeT_s[H_ * H_];   // 32 KB, rows = h, XOR-swizzled
  __shared__ __align__(16) bhalf es[64 * H_];      // 16 KB, rows = j, swizzled; reused as bounce
  __shared__ float cvi_s[H_];
  __shared__ float red[4 * 4 * 64];                // 4 KB

  const int t = threadIdx.x;
  const int bi = blockIdx.x >> 2;
  const int jq = blockIdx.x & 3;
  const int b = bi >> 8;
  const int lane = t & 63, w = t >> 6;
  const int c = lane & 15, q = lane >> 4;
  const int jw = w & 1, hw = w >> 1;
  const int wbase = t & 192;  // w*64

  // ---- async stage UeT (32 KB) and e tile (16 KB), source-XOR-swizzled ----
#pragma unroll
  for (int r = 0; r < 8; ++r) {
    int s = r * 256 + t;
    int row = s >> 4, ckL = s & 15;
    gl2lds16(UeT_g + row * H_ + (ckL ^ (row & 15)) * 8,
             &UeT_s[(size_t)(r * 256 + wbase) * 8]);
  }
  {
    const bhalf* esrc = e + ((size_t)bi * V_ + jq * 64) * H_;
#pragma unroll
    for (int r = 0; r < 4; ++r) {
      int s = r * 256 + t;
      int row = s >> 4, ckL = s & 15;
      gl2lds16(esrc + row * H_ + (ckL ^ (row & 15)) * 8,
               &es[(size_t)(r * 256 + wbase) * 8]);
    }
  }
  if (t < H_) cvi_s[t] = bUe[t] + VV[(size_t)bi * H_ + t].x;

  // ---- prefetch VV tile fragment into registers (overlaps staging+MFMA) ----
  float2 vvr[2][4][4];
  {
    const float2* vvb = VV + ((size_t)b * V_ + jq * 64 + jw * 32) * H_ + hw * 64;
#pragma unroll
    for (int m = 0; m < 2; ++m)
#pragma unroll
      for (int n = 0; n < 4; ++n)
#pragma unroll
        for (int r = 0; r < 4; ++r)
          vvr[m][n][r] = vvb[(m * 16 + q * 4 + r) * H_ + n * 16 + c];
  }
  __syncthreads();  // drains global_load_lds + our register loads

  // ---- K loop ----
  f32x4 acc[2][4];
#pragma unroll
  for (int m = 0; m < 2; ++m)
#pragma unroll
    for (int n = 0; n < 4; ++n) acc[m][n] = {0.f, 0.f, 0.f, 0.f};
#pragma unroll
  for (int k0 = 0; k0 < 4; ++k0) {
    bf16x8 af[2], bfr[4];
#pragma unroll
    for (int m = 0; m < 2; ++m) {
      int row = jw * 32 + m * 16 + c;
      af[m] = *(const bf16x8*)&es[row * H_ + (((k0 * 4 + q) ^ c) * 8)];
    }
#pragma unroll
    for (int n = 0; n < 4; ++n) {
      int row = hw * 64 + n * 16 + c;
      bfr[n] = *(const bf16x8*)&UeT_s[row * H_ + (((k0 * 4 + q) ^ c) * 8)];
    }
#pragma unroll
    for (int m = 0; m < 2; ++m)
#pragma unroll
      for (int n = 0; n < 4; ++n)
        acc[m][n] = __builtin_amdgcn_mfma_f32_16x16x32_bf16(af[m], bfr[n], acc[m][n], 0, 0, 0);
  }
  __syncthreads();  // all waves done reading es; es becomes bounce buffer

  // ---- epilogue ----
  float aN[4] = {0, 0, 0, 0}, aD[4] = {0, 0, 0, 0};
  float bS[4] = {0, 0, 0, 0}, bS2[4] = {0, 0, 0, 0};
#pragma unroll
  for (int m = 0; m < 2; ++m) {
#pragma unroll
    for (int n = 0; n < 4; ++n) {
#pragma unroll
      for (int r = 0; r < 4; ++r) {
        int j_ip = jw * 32 + m * 16 + q * 4 + r;
        int h = hw * 64 + n * 16 + c;
        float etv = acc[m][n][r] + cvi_s[h] + vvr[m][n][r].x;
        float g = 1.f / (1.f + __expf(-etv));
        aN[n] += g * vvr[m][n][r].y; aD[n] += g; bS[n] += etv; bS2[n] += etv * etv;
        if (et != 0)
          es[j_ip * H_ + (((h >> 3) ^ (j_ip & 15)) * 8) + (h & 7)] = f2bf(etv);
      }
    }
  }
  // partial reductions: over q via shfl, stash per-wave into red
#pragma unroll
  for (int n = 0; n < 4; ++n) {
    aN[n] += __shfl_xor(aN[n], 16);  aN[n] += __shfl_xor(aN[n], 32);
    aD[n] += __shfl_xor(aD[n], 16);  aD[n] += __shfl_xor(aD[n], 32);
    bS[n] += __shfl_xor(bS[n], 16);  bS[n] += __shfl_xor(bS[n], 32);
    bS2[n] += __shfl_xor(bS2[n], 16); bS2[n] += __shfl_xor(bS2[n], 32);
  }
  if (lane < 16) {
#pragma unroll
    for (int n = 0; n < 4; ++n) {
      int hl = n * 16 + c;
      red[(0 * 4 + w) * 64 + hl] = aN[n];
      red[(1 * 4 + w) * 64 + hl] = aD[n];
      red[(2 * 4 + w) * 64 + hl] = bS[n];
      red[(3 * 4 + w) * 64 + hl] = bS2[n];
    }
  }
  __syncthreads();

  // ---- coalesced bounce -> e_tmp, and per-block partial stores ----
  if (et != 0) {
#pragma unroll
    for (int it = 0; it < 4; ++it) {
      int slot = it * 256 + t;
      int jj = slot >> 4, ck = slot & 15;
      uint4 v = *(const uint4*)&es[jj * H_ + ((ck ^ (jj & 15)) * 8)];
      *(uint4*)&et[((size_t)bi * V_ + jq * 64 + jj) * H_ + ck * 8] = v;
    }
  }
  if (t < H_) {
    int hw2 = t >> 6, hl = t & 63;
    int w0 = hw2 * 2, w1 = w0 + 1;
    size_t o = ((size_t)jq * BV_ + bi) * H_ + t;
    aggN[o]   = red[(0 * 4 + w0) * 64 + hl] + red[(0 * 4 + w1) * 64 + hl];
    aggD[o]   = red[(1 * 4 + w0) * 64 + hl] + red[(1 * 4 + w1) * 64 + hl];
    bn_ps[o]  = red[(2 * 4 + w0) * 64 + hl] + red[(2 * 4 + w1) * 64 + hl];
    bn_ps2[o] = red[(3 * 4 + w0) * 64 + hl] + red[(3 * 4 + w1) * 64 + hl];
  }
}

// ---------------- finalize e BN stats (sums 4096 partials) ----------------
__global__ void __launch_bounds__(256) k3_estats(const float* __restrict__ bn_ps,
                                                 const float* __restrict__ bn_ps2,
                                                 float* __restrict__ mu_rs) {
  __shared__ float r1[256], r2[256];
  int h = blockIdx.x, t = threadIdx.x;
  float s = 0, s2 = 0;
#pragma unroll 4
  for (int r = 0; r < 16; ++r) {
    int blk = r * 256 + t;
    s += bn_ps[(size_t)blk * H_ + h];
    s2 += bn_ps2[(size_t)blk * H_ + h];
  }
  r1[t] = s; r2[t] = s2; __syncthreads();
  for (int st = 128; st > 0; st >>= 1) {
    if (t < st) { r1[t] += r1[t + st]; r2[t] += r2[t + st]; }
    __syncthreads();
  }
  if (t == 0) {
    const float inv = 1.f / 262144.f;
    float mu = r1[0] * inv;
    float var = r2[0] * inv - mu * mu;
    mu_rs[h] = mu;
    mu_rs[H_ + h] = rsqrtf(var + 1e-5f);
  }
}

// ---------------- x update (sums 4 jq agg partials) ----------------
__global__ void __launch_bounds__(256) k4_xupd(float* __restrict__ x,
                                               const float* __restrict__ Unx,
                                               const float* __restrict__ aggN,
                                               const float* __restrict__ aggD,
                                               const float* __restrict__ g_x,
                                               const float* __restrict__ bx_bn) {
  __shared__ float red[256], red2[256];
  int h = blockIdx.x, t = threadIdx.x;
  float xt[4];
  float s = 0, s2 = 0;
#pragma unroll
  for (int r = 0; r < 4; ++r) {
    int idx = r * 256 + t;
    float sN = 0, sD = 0;
#pragma unroll
    for (int jq = 0; jq < 4; ++jq) {
      size_t o = ((size_t)jq * BV_ + idx) * H_ + h;
      sN += aggN[o]; sD += aggD[o];
    }
    float v = Unx[(size_t)idx * H_ + h] + sN / (sD + 1e-20f);
    xt[r] = v; s += v; s2 += v * v;
  }
  red[t] = s; red2[t] = s2; __syncthreads();
  for (int st = 128; st > 0; st >>= 1) {
    if (t < st) { red[t] += red[t + st]; red2[t] += red2[t + st]; }
    __syncthreads();
  }
  float mu = red[0] * (1.f / 1024.f);
  float var = red2[0] * (1.f / 1024.f) - mu * mu;
  float rs = rsqrtf(var + 1e-5f);
  float g = g_x[h], bb = bx_bn[h];
#pragma unroll
  for (int r = 0; r < 4; ++r) {
    int idx = r * 256 + t;
    size_t o = (size_t)idx * H_ + h;
    float v = g * (xt[r] - mu) * rs + bb;
    if (v > 0.f) x[o] += v;
  }
}

// ---------------- e update from stored e_tmp ----------------
__global__ void __launch_bounds__(256) k5_eupd(bhalf* __restrict__ e,
                                               const bhalf* __restrict__ e_tmp,
                                               const float* __restrict__ g_e,
                                               const float* __restrict__ be_bn,
                                               const float* __restrict__ mu_rs) {
  __shared__ float sc[H_], sh[H_];
  int t = threadIdx.x;
  if (t < H_) {
    float mu = mu_rs[t], rs = mu_rs[H_ + t];
    float g = g_e[t], bb = be_bn[t];
    sc[t] = g * rs;
    sh[t] = bb - g * rs * mu;
  }
  __syncthreads();
  size_t base = ((size_t)blockIdx.x * 256 + t) * 8;
  int h0 = (int)(base & 127);
  uint4 pe = *(const uint4*)(e + base);
  uint4 pt = *(const uint4*)(e_tmp + base);
  float ev[8], tv[8];
  unpack8(pe, ev); unpack8(pt, tv);
#pragma unroll
  for (int m = 0; m < 8; ++m) {
    int h = h0 + m;
    float v = sc[h] * tv[m] + sh[h];
    if (v > 0.f) ev[m] += v;
  }
  uint4 st;
  st.x = pack2(ev[0], ev[1]); st.y = pack2(ev[2], ev[3]);
  st.z = pack2(ev[4], ev[5]); st.w = pack2(ev[6], ev[7]);
  *(uint4*)(e + base) = st;
}

// ---------------- readout ----------------
__global__ void k6_readout(const float* __restrict__ x, const float* __restrict__ W1,
                           const float* __restrict__ b1, const float* __restrict__ W2,
                           float* __restrict__ out_acc) {
  __shared__ float xs[H_];
  __shared__ float red[H_];
  int bi = blockIdx.x, h = threadIdx.x;
  int b = bi >> 8;
  xs[h] = x[(size_t)bi * H_ + h];
  __syncthreads();
  float a = b1[h];
#pragma unroll 8
  for (int k = 0; k < H_; ++k) a += xs[k] * W1[k * H_ + h];
  a = fmaxf(a, 0.f) * W2[h];
  red[h] = a; __syncthreads();
  for (int s = 64; s > 0; s >>= 1) {
    if (h < s) red[h] += red[h + s];
    __syncthreads();
  }
  if (h == 0) atomicAdd(&out_acc[b], red[0]);
}

__global__ void k7_final(const float* __restrict__ out_acc,
                         const float* __restrict__ b_mlp2, float* __restrict__ out) {
  int t = threadIdx.x;
  if (t < 4) out[t] = out_acc[t] * (1.f / 256.f) + b_mlp2[0];
}

extern "C" void kernel_launch(void* const* d_in, const int* in_sizes, int n_in,
                              void* d_out, int out_size, void* d_ws, size_t ws_size,
                              hipStream_t stream) {
  (void)in_sizes; (void)out_size; (void)ws_size;
  const int off = n_in - 26;  // tolerate pruned x_edges
  const float* x_ev    = (const float*)d_in[off + 0];
  const float* x_coord = (const float*)d_in[off + 1];
  const float* x_tour  = (const float*)d_in[off + 2];
  const float* x_btour = (const float*)d_in[off + 3];
  const float* W_node  = (const float*)d_in[off + 4];
  const float* b_node  = (const float*)d_in[off + 5];
  const float* W_eval  = (const float*)d_in[off + 6];
  const float* b_eval  = (const float*)d_in[off + 7];
  const float* W_ecat  = (const float*)d_in[off + 8];
  const float* b_ecat  = (const float*)d_in[off + 9];
  const float* Ue      = (const float*)d_in[off + 10];
  const float* bUe     = (const float*)d_in[off + 11];
  const float* Ve      = (const float*)d_in[off + 12];
  const float* bVe     = (const float*)d_in[off + 13];
  const float* Un      = (const float*)d_in[off + 14];
  const float* bUn     = (const float*)d_in[off + 15];
  const float* Vn      = (const float*)d_in[off + 16];
  const float* bVn     = (const float*)d_in[off + 17];
  const float* g_e     = (const float*)d_in[off + 18];
  const float* be_bn   = (const float*)d_in[off + 19];
  const float* g_x     = (const float*)d_in[off + 20];
  const float* bx_bn   = (const float*)d_in[off + 21];
  const float* W_mlp1  = (const float*)d_in[off + 22];
  const float* b_mlp1  = (const float*)d_in[off + 23];
  const float* W_mlp2  = (const float*)d_in[off + 24];
  const float* b_mlp2  = (const float*)d_in[off + 25];

  char* ws = (char*)d_ws;
  float*  x      = (float*)(ws + 0x000000);
  float2* VV     = (float2*)(ws + 0x080000);     // 1 MB: (Vex,Vnx)
  float*  Unx    = (float*)(ws + 0x180000);
  float*  aggN   = (float*)(ws + 0x200000);      // 2 MB: [4][BV][H]
  float*  aggD   = (float*)(ws + 0x400000);      // 2 MB
  float*  bn_ps  = (float*)(ws + 0x600000);      // 2 MB
  float*  bn_ps2 = (float*)(ws + 0x800000);      // 2 MB
  float*  mu_rs  = (float*)(ws + 0xA00000);
  float*  out_acc= (float*)(ws + 0xA00400);
  bhalf*  UeT_g  = (bhalf*)(ws + 0xA01000);      // 96 KB: 3 layers pre-transposed bf16
  bhalf*  e      = (bhalf*)(ws + 0xA20000);                  // 64 MiB
  bhalf*  e_tmp  = (bhalf*)(ws + 0xA20000 + 0x4000000);      // 64 MiB

  k_init<<<1, 64, 0, stream>>>(out_acc);
  VRPValueNet_66924180407123_kernel<<<1, 64, 0, stream>>>();
  k_prep<<<NL_, 256, 0, stream>>>(Ue, UeT_g);
  k0_x<<<BV_, H_, 0, stream>>>(x_coord, W_node, b_node, x);
  k0_e<<<BV_, 256, 0, stream>>>(x_ev, x_tour, x_btour, W_eval, b_eval, W_ecat, b_ecat, e);

  for (int l = 0; l < NL_; ++l) {
    const float* Ve_l = Ve + l * H_ * H_;
    const float* Un_l = Un + l * H_ * H_;
    const float* Vn_l = Vn + l * H_ * H_;
    const float* bUe_l = bUe + l * H_;
    const float* bVe_l = bVe + l * H_;
    const float* bUn_l = bUn + l * H_;
    const float* bVn_l = bVn + l * H_;
    const float* g_e_l = g_e + l * H_;
    const float* be_l  = be_bn + l * H_;
    const float* g_x_l = g_x + l * H_;
    const float* bx_l  = bx_bn + l * H_;
    const bhalf* UeT_l = UeT_g + l * H_ * H_;
    const bool need_e_next = (l < NL_ - 1);

    k1_xproj<<<BV_, H_, 0, stream>>>(x, Ve_l, bVe_l, Vn_l, bVn_l, Un_l, bUn_l, VV, Unx);
    k2_edge<<<BV_ * 4, 256, 0, stream>>>(e, need_e_next ? e_tmp : (bhalf*)0,
                                         UeT_l, bUe_l, VV, aggN, aggD, bn_ps, bn_ps2);
    if (need_e_next) {
      k3_estats<<<H_, 256, 0, stream>>>(bn_ps, bn_ps2, mu_rs);
      k5_eupd<<<16384, 256, 0, stream>>>(e, e_tmp, g_e_l, be_l, mu_rs);
    }
    k4_xupd<<<H_, 256, 0, stream>>>(x, Unx, aggN, aggD, g_x_l, bx_l);
  }

  k6_readout<<<BV_, H_, 0, stream>>>(x, W_mlp1, b_mlp1, W_mlp2, out_acc);
  k7_final<<<1, 64, 0, stream>>>(out_acc, b_mlp2, (float*)d_out);
}